// Round 1
// 746.658 us; speedup vs baseline: 1.1110x; 1.1110x over previous
//
#include <hip/hip_runtime.h>
#include <hip/hip_bf16.h>
#include <cstdint>

typedef __bf16 bf16;
typedef __bf16 bf16x8 __attribute__((ext_vector_type(8)));
typedef float f32x4 __attribute__((ext_vector_type(4)));
typedef float f32x8 __attribute__((ext_vector_type(8)));
typedef uint32_t u32x4 __attribute__((ext_vector_type(4)));

constexpr int Bz = 4, T = 2048, Cdim = 2048, NH = 16, HD = 128;
constexpr int QKVC = 3 * Cdim; // 6144
constexpr int QKC = 2 * Cdim;  // 4096 (q|k buffer row stride)
constexpr float NEG_BIG = -3.0e4f;

// async global->LDS, 16B per lane; l must be the WAVE-UNIFORM base
__device__ __forceinline__ void load_lds16(const bf16* g, const bf16* l) {
  __builtin_amdgcn_global_load_lds(
      (const __attribute__((address_space(1))) void*)g,
      (__attribute__((address_space(3))) void*)l, 16, 0, 0);
}

__device__ __forceinline__ uint32_t pack2bf(float lo, float hi) {
  uint16_t a = __builtin_bit_cast(uint16_t, (bf16)lo);
  uint16_t b = __builtin_bit_cast(uint16_t, (bf16)hi);
  return ((uint32_t)b << 16) | (uint32_t)a;
}

// -------------------------------------------------- fp32 -> bf16 convert
__global__ __launch_bounds__(256)
void cvt_bf16_k(const float* __restrict__ in, bf16* __restrict__ out) {
  size_t i = (size_t)blockIdx.x * 256 + threadIdx.x;
  f32x8 v = *(const f32x8*)(in + i * 8);
  bf16x8 h;
#pragma unroll
  for (int j = 0; j < 8; ++j) h[j] = (bf16)v[j];
  *(bf16x8*)(out + i * 8) = h;
}

// -------------------------------------------------- fp32 -> bf16 transpose
__global__ __launch_bounds__(256)
void transpose_cvt_k(const float* __restrict__ in, bf16* __restrict__ out,
                     int R, int Ccols) {
  __shared__ bf16 tile[32][33];
  int c0 = blockIdx.x * 32, r0 = blockIdx.y * 32;
  int tx = threadIdx.x, ty = threadIdx.y; // block (32,8)
#pragma unroll
  for (int i = 0; i < 4; ++i)
    tile[ty + i * 8][tx] = (bf16)in[(size_t)(r0 + ty + i * 8) * Ccols + c0 + tx];
  __syncthreads();
#pragma unroll
  for (int i = 0; i < 4; ++i)
    out[(size_t)(c0 + ty + i * 8) * R + r0 + tx] = tile[tx][ty + i * 8];
}

// -------------------------------------------------- GEMM C = A * BT^T
// A [M,K] bf16, BT [N,K] bf16. Staging via global_load_lds (16B/lane).
// Normal cols -> Craw (fp32 if CF32 else bf16, row stride ldc).
// If SCATV: cols >= QKC scatter to Vt[b][h][d][T] (bf16).
template <bool CF32, bool SCATV>
__global__ __launch_bounds__(256)
void gemm_bt_k(const bf16* __restrict__ A, const bf16* __restrict__ BT,
               void* __restrict__ Craw, bf16* __restrict__ Vt,
               int M, int N, int K, int ldc) {
  __shared__ __align__(16) bf16 As[128 * 32];
  __shared__ __align__(16) bf16 Bs[128 * 32];

  int tid = threadIdx.x;
  int w = tid >> 6, lane = tid & 63;
  int qn = lane & 15, quad = lane >> 4;
  int wm = (w >> 1) * 64, wn = (w & 1) * 64;
  size_t row0 = (size_t)blockIdx.y * 128;
  size_t col0 = (size_t)blockIdx.x * 128;

  f32x4 zero4 = {0.f, 0.f, 0.f, 0.f};
  f32x4 acc[4][4];
#pragma unroll
  for (int i = 0; i < 4; ++i)
#pragma unroll
    for (int j = 0; j < 4; ++j) acc[i][j] = zero4;

  // staging: wave w stages 16-row chunks {2w, 2w+1} of both tiles.
  // lane -> (row=lane>>2, 8-elem col chunk=(lane&3)*8): LDS offset == lane*16B.
  int r16 = lane >> 2;
  int kcl = (lane & 3) << 3;
  const bf16* aBase = A + (row0 + w * 32 + r16) * (size_t)K + kcl;
  const bf16* bBase = BT + (col0 + w * 32 + r16) * (size_t)K + kcl;
  const bf16* aU0 = &As[(w * 2) * 512];
  const bf16* aU1 = &As[(w * 2 + 1) * 512];
  const bf16* bU0 = &Bs[(w * 2) * 512];
  const bf16* bU1 = &Bs[(w * 2 + 1) * 512];

  for (int k0 = 0; k0 < K; k0 += 32) {
    __syncthreads();
    load_lds16(aBase + k0, aU0);
    load_lds16(aBase + (size_t)16 * K + k0, aU1);
    load_lds16(bBase + k0, bU0);
    load_lds16(bBase + (size_t)16 * K + k0, bU1);
    __syncthreads();

    bf16x8 aFr[4], bFr[4];
#pragma unroll
    for (int i = 0; i < 4; ++i)
      aFr[i] = *(const bf16x8*)&As[(wm + i * 16 + qn) * 32 + quad * 8];
#pragma unroll
    for (int j = 0; j < 4; ++j)
      bFr[j] = *(const bf16x8*)&Bs[(wn + j * 16 + qn) * 32 + quad * 8];
#pragma unroll
    for (int i = 0; i < 4; ++i)
#pragma unroll
      for (int j = 0; j < 4; ++j)
        acc[i][j] = __builtin_amdgcn_mfma_f32_16x16x32_bf16(aFr[i], bFr[j], acc[i][j], 0, 0, 0);
  }

  if (SCATV && (int)col0 >= QKC) {
    int hh = (int)((col0 - QKC) >> 7); // whole block maps to one head
#pragma unroll
    for (int i = 0; i < 4; ++i)
#pragma unroll
      for (int j = 0; j < 4; ++j)
#pragma unroll
        for (int rr = 0; rr < 4; ++rr) {
          int row = (int)row0 + wm + i * 16 + quad * 4 + rr;
          int bb = row >> 11, tt = row & (T - 1);
          int d = wn + j * 16 + qn;
          Vt[((size_t)(bb * NH + hh) * HD + d) * T + tt] = (bf16)acc[i][j][rr];
        }
  } else {
#pragma unroll
    for (int i = 0; i < 4; ++i)
#pragma unroll
      for (int j = 0; j < 4; ++j)
#pragma unroll
        for (int rr = 0; rr < 4; ++rr) {
          size_t idx = (row0 + wm + i * 16 + quad * 4 + rr) * (size_t)ldc +
                       col0 + wn + j * 16 + qn;
          if (CF32) ((float*)Craw)[idx] = acc[i][j][rr];
          else      ((bf16*)Craw)[idx] = (bf16)acc[i][j][rr];
        }
  }
}

// -------------------------------------------------- flash attention
// qk: [B, T, 2C] bf16 (q | k). vt: [B,H,HD,T] bf16. y: [B,T,C] bf16.
// 512 threads = 8 waves; Q-tile 128 (16 rows/wave); K-tile 64.
// Swapped QK^T: St = mfma(K,Q) so each lane owns P[q=lane&15][16 k-vals].
// P never touches LDS (ds_bpermute redistribution to A-frag layout).
constexpr int KSTR = 136, VSTR = 72;

__global__ __launch_bounds__(512, 4)
void attn_k(const bf16* __restrict__ qk, const bf16* __restrict__ vt,
            bf16* __restrict__ y) {
  const int b = blockIdx.z, h = blockIdx.y;
  const int qb = (int)(gridDim.x - 1 - blockIdx.x); // heavy blocks first
  const int qt0 = qb * 128;
  const int tid = threadIdx.x;
  const int w = tid >> 6, lane = tid & 63;
  const int qn = lane & 15, quad = lane >> 4;
  const int q0 = qt0 + w * 16;

  __shared__ __align__(16) bf16 Ks[64 * KSTR];  // [key][hd], padded
  __shared__ __align__(16) bf16 Vs[128 * VSTR]; // [hd][key], padded

  const bf16* qkB = qk + (size_t)b * T * QKC + h * HD;
  const bf16* vtB = vt + (size_t)(b * NH + h) * HD * T;
  const bf16* kBase = qkB + Cdim; // k section

  // Q fragment (B-operand layout), pre-scaled by 1/sqrt(hd)
  bf16x8 qF[4];
  {
    const float scale = 0.088388347648318447f; // 1/sqrt(128)
    const bf16* qRow = qkB + (size_t)(q0 + qn) * QKC;
#pragma unroll
    for (int c = 0; c < 4; ++c) {
      bf16x8 v = *(const bf16x8*)(qRow + c * 32 + quad * 8);
#pragma unroll
      for (int j = 0; j < 8; ++j) v[j] = (bf16)((float)v[j] * scale);
      qF[c] = v;
    }
  }

  float m_i = NEG_BIG, l_i = 0.f;
  f32x4 zero4 = {0.f, 0.f, 0.f, 0.f};
  f32x4 o[8];
#pragma unroll
  for (int cc = 0; cc < 8; ++cc) o[cc] = zero4;

  const int kr  = tid >> 4;        // 0..31
  const int kc8 = (tid & 15) << 3; // 0..120
  const int vd  = tid >> 3;        // 0..63
  const int vk8 = (tid & 7) << 3;  // 0..56

  // bpermute byte addresses for P redistribution (cross-quad, same qn)
  const int addrA = ((lane & 15) + ((quad & 1) << 5)) << 2; // src quad (quad&1)*2
  const int addrB = addrA + 64;                             // src quad (quad&1)*2+1

  const int nT = 2 * qb + 2;

  // prologue: issue global loads for tile 0 (async-stage split, T14)
  bf16x8 rK0 = *(const bf16x8*)(kBase + (size_t)kr * QKC + kc8);
  bf16x8 rK1 = *(const bf16x8*)(kBase + (size_t)(kr + 32) * QKC + kc8);
  bf16x8 rV0 = *(const bf16x8*)(vtB + (size_t)vd * T + vk8);
  bf16x8 rV1 = *(const bf16x8*)(vtB + (size_t)(vd + 64) * T + vk8);

  for (int t = 0; t < nT; ++t) {
    const int kt0 = t * 64;
    __syncthreads(); // prev tile's LDS reads done
    *(bf16x8*)&Ks[kr * KSTR + kc8] = rK0;
    *(bf16x8*)&Ks[(kr + 32) * KSTR + kc8] = rK1;
    *(bf16x8*)&Vs[vd * VSTR + vk8] = rV0;
    *(bf16x8*)&Vs[(vd + 64) * VSTR + vk8] = rV1;
    __syncthreads(); // LDS tile ready
    if (t + 1 < nT) { // issue next tile's loads; latency hides under compute
      const int kn = kt0 + 64;
      rK0 = *(const bf16x8*)(kBase + (size_t)(kn + kr) * QKC + kc8);
      rK1 = *(const bf16x8*)(kBase + (size_t)(kn + kr + 32) * QKC + kc8);
      rV0 = *(const bf16x8*)(vtB + (size_t)vd * T + kn + vk8);
      rV1 = *(const bf16x8*)(vtB + (size_t)(vd + 64) * T + kn + vk8);
    }
    if (kt0 > q0 + 15) continue; // wave-uniform; barriers already passed

    // ---- St = K Q^T (swapped): s[ks][rr] = S[q0+qn][kt0+ks*16+quad*4+rr]
    f32x4 s[4] = {zero4, zero4, zero4, zero4};
    __builtin_amdgcn_s_setprio(1);
#pragma unroll
    for (int c = 0; c < 4; ++c)
#pragma unroll
      for (int ks = 0; ks < 4; ++ks) {
        bf16x8 kf = *(const bf16x8*)&Ks[(ks * 16 + qn) * KSTR + c * 32 + quad * 8];
        s[ks] = __builtin_amdgcn_mfma_f32_16x16x32_bf16(kf, qF[c], s[ks], 0, 0, 0);
      }
    __builtin_amdgcn_s_setprio(0);

    // ---- causal mask (active waves have kt0 <= q0, never fully-masked rows)
    if (kt0 + 63 > q0) {
      const int qv = q0 + qn;
#pragma unroll
      for (int ks = 0; ks < 4; ++ks)
#pragma unroll
        for (int rr = 0; rr < 4; ++rr)
          if (kt0 + ks * 16 + quad * 4 + rr > qv) s[ks][rr] = NEG_BIG;
    }

    // ---- tile max: 15 local + 2 shuffles (k is quad-split per qn)
    float mx = s[0][0];
#pragma unroll
    for (int ks = 0; ks < 4; ++ks)
#pragma unroll
      for (int rr = 0; rr < 4; ++rr) mx = fmaxf(mx, s[ks][rr]);
    mx = fmaxf(mx, __shfl_xor(mx, 16));
    mx = fmaxf(mx, __shfl_xor(mx, 32));

    // ---- defer-max rescale (T13): only when max actually grows past THR
    if (!__all(mx - m_i <= 8.0f)) {
      float mn = fmaxf(m_i, mx);
      float alpha = __expf(m_i - mn);
      m_i = mn;
      l_i *= alpha;
      float aR[4];
#pragma unroll
      for (int rr = 0; rr < 4; ++rr) aR[rr] = __shfl(alpha, quad * 4 + rr);
#pragma unroll
      for (int cc = 0; cc < 8; ++cc)
#pragma unroll
        for (int rr = 0; rr < 4; ++rr) o[cc][rr] *= aR[rr];
    }

    // ---- P = exp(S - m), row-sum (in place)
    float rs = 0.f;
#pragma unroll
    for (int ks = 0; ks < 4; ++ks)
#pragma unroll
      for (int rr = 0; rr < 4; ++rr) {
        float pv = __expf(s[ks][rr] - m_i);
        s[ks][rr] = pv;
        rs += pv;
      }
    rs += __shfl_xor(rs, 16);
    rs += __shfl_xor(rs, 32);
    l_i += rs;

    // ---- pack P to bf16 pairs: pku[ks][b] = (P[k=ks*16+quad*4+2b], +1)
    uint32_t pku[4][2];
#pragma unroll
    for (int ks = 0; ks < 4; ++ks)
#pragma unroll
      for (int b2 = 0; b2 < 2; ++b2)
        pku[ks][b2] = pack2bf(s[ks][2 * b2], s[ks][2 * b2 + 1]);

    // ---- redistribute to A-frag layout: pa[c][j] = P[qn][c*32+quad*8+j]
    // src lane = qn + 16*((quad&1)*2 + (j>>2)); src reg ks = 2c + (quad>>1)
    const int hi2 = quad >> 1;
    __builtin_amdgcn_s_setprio(1);
#pragma unroll
    for (int c = 0; c < 2; ++c) {
      uint32_t lo0A = (uint32_t)__builtin_amdgcn_ds_bpermute(addrA, (int)pku[2 * c][0]);
      uint32_t lo1A = (uint32_t)__builtin_amdgcn_ds_bpermute(addrA, (int)pku[2 * c][1]);
      uint32_t lo0B = (uint32_t)__builtin_amdgcn_ds_bpermute(addrB, (int)pku[2 * c][0]);
      uint32_t lo1B = (uint32_t)__builtin_amdgcn_ds_bpermute(addrB, (int)pku[2 * c][1]);
      uint32_t hi0A = (uint32_t)__builtin_amdgcn_ds_bpermute(addrA, (int)pku[2 * c + 1][0]);
      uint32_t hi1A = (uint32_t)__builtin_amdgcn_ds_bpermute(addrA, (int)pku[2 * c + 1][1]);
      uint32_t hi0B = (uint32_t)__builtin_amdgcn_ds_bpermute(addrB, (int)pku[2 * c + 1][0]);
      uint32_t hi1B = (uint32_t)__builtin_amdgcn_ds_bpermute(addrB, (int)pku[2 * c + 1][1]);
      u32x4 pw;
      pw[0] = hi2 ? hi0A : lo0A; // j=0,1
      pw[1] = hi2 ? hi1A : lo1A; // j=2,3
      pw[2] = hi2 ? hi0B : lo0B; // j=4,5
      pw[3] = hi2 ? hi1B : lo1B; // j=6,7
      bf16x8 pF = __builtin_bit_cast(bf16x8, pw);
#pragma unroll
      for (int cc = 0; cc < 8; ++cc) {
        bf16x8 vf = *(const bf16x8*)&Vs[(cc * 16 + qn) * VSTR + c * 32 + quad * 8];
        o[cc] = __builtin_amdgcn_mfma_f32_16x16x32_bf16(pF, vf, o[cc], 0, 0, 0);
      }
    }
    __builtin_amdgcn_s_setprio(0);
  }

  // ---- epilogue: broadcast l to O's row layout (q = quad*4+rr)
  float linv[4];
#pragma unroll
  for (int rr = 0; rr < 4; ++rr) {
    float lr = __shfl(l_i, quad * 4 + rr);
    linv[rr] = 1.f / fmaxf(lr, 1e-30f);
  }
  bf16* yB = y + (size_t)b * T * Cdim + h * HD;
#pragma unroll
  for (int cc = 0; cc < 8; ++cc)
#pragma unroll
    for (int rr = 0; rr < 4; ++rr)
      yB[(size_t)(q0 + quad * 4 + rr) * Cdim + cc * 16 + qn] =
          (bf16)(o[cc][rr] * linv[rr]);
}

// -------------------------------------------------- launch
extern "C" void kernel_launch(void* const* d_in, const int* in_sizes, int n_in,
                              void* d_out, int out_size, void* d_ws, size_t ws_size,
                              hipStream_t stream) {
  const float* x     = (const float*)d_in[0]; // [4,2048,2048] fp32
  const float* Wqkv  = (const float*)d_in[1]; // [2048,6144]  fp32
  const float* Wproj = (const float*)d_in[2]; // [2048,2048]  fp32
  float* out = (float*)d_out;                 // [4,2048,2048] fp32

  char* ws = (char*)d_ws;
  // ws: [0,64M) qk bf16. [64M,96M) Vt bf16. [96M,120M) WqkvT (dead after
  // gemm1) / y bf16 aliases [96M,128M). [128M,136M) WprojT. Total 136 MiB.
  // xb (bf16 copy of x, 32MB) lives in d_out, which is dead until gemm2
  // fully overwrites it.
  bf16* qkbuf  = (bf16*)(ws);
  bf16* Vt     = (bf16*)(ws + (size_t)64 * 1024 * 1024);
  bf16* WqkvT  = (bf16*)(ws + (size_t)96 * 1024 * 1024);
  bf16* y      = WqkvT; // alias, sequenced
  bf16* WprojT = (bf16*)(ws + (size_t)128 * 1024 * 1024);
  bf16* xb     = (bf16*)d_out; // scratch until gemm2 overwrites

  cvt_bf16_k<<<dim3((Bz * T * Cdim) / (256 * 8)), 256, 0, stream>>>(x, xb);
  transpose_cvt_k<<<dim3(QKVC / 32, Cdim / 32), dim3(32, 8), 0, stream>>>(
      Wqkv, WqkvT, Cdim, QKVC);
  transpose_cvt_k<<<dim3(Cdim / 32, Cdim / 32), dim3(32, 8), 0, stream>>>(
      Wproj, WprojT, Cdim, Cdim);

  // qkv GEMM: q,k -> qkbuf; v -> Vt (scattered transposed)
  gemm_bt_k<false, true><<<dim3(QKVC / 128, (Bz * T) / 128), 256, 0, stream>>>(
      xb, WqkvT, (void*)qkbuf, Vt, Bz * T, QKVC, Cdim, QKC);

  // causal flash attention
  attn_k<<<dim3(T / 128, NH, Bz), 512, 0, stream>>>(qkbuf, Vt, y);

  // out = y @ Wproj
  gemm_bt_k<true, false><<<dim3(Cdim / 128, (Bz * T) / 128), 256, 0, stream>>>(
      y, WprojT, (void*)out, nullptr, Bz * T, Cdim, Cdim, Cdim);
}

// Round 2
// 603.769 us; speedup vs baseline: 1.3739x; 1.2367x over previous
//
#include <hip/hip_runtime.h>
#include <hip/hip_bf16.h>
#include <cstdint>

typedef __bf16 bf16;
typedef __bf16 bf16x8 __attribute__((ext_vector_type(8)));
typedef float f32x4 __attribute__((ext_vector_type(4)));
typedef float f32x8 __attribute__((ext_vector_type(8)));
typedef uint32_t u32x4 __attribute__((ext_vector_type(4)));

constexpr int Bz = 4, T = 2048, Cdim = 2048, NH = 16, HD = 128;
constexpr int QKVC = 3 * Cdim; // 6144
constexpr int QKC = 2 * Cdim;  // 4096 (q|k buffer row stride)
constexpr float NEG_BIG = -3.0e4f;

// async global->LDS, 16B per lane; l must be the WAVE-UNIFORM base
__device__ __forceinline__ void load_lds16(const bf16* g, const bf16* l) {
  __builtin_amdgcn_global_load_lds(
      (const __attribute__((address_space(1))) void*)g,
      (__attribute__((address_space(3))) void*)l, 16, 0, 0);
}

__device__ __forceinline__ uint32_t pack2bf(float lo, float hi) {
  uint16_t a = __builtin_bit_cast(uint16_t, (bf16)lo);
  uint16_t b = __builtin_bit_cast(uint16_t, (bf16)hi);
  return ((uint32_t)b << 16) | (uint32_t)a;
}

// -------------------------------------------------- fp32 -> bf16 convert
__global__ __launch_bounds__(256)
void cvt_bf16_k(const float* __restrict__ in, bf16* __restrict__ out) {
  size_t i = (size_t)blockIdx.x * 256 + threadIdx.x;
  f32x8 v = *(const f32x8*)(in + i * 8);
  bf16x8 h;
#pragma unroll
  for (int j = 0; j < 8; ++j) h[j] = (bf16)v[j];
  *(bf16x8*)(out + i * 8) = h;
}

// -------------------------------------------------- fp32 -> bf16 transpose
__global__ __launch_bounds__(256)
void transpose_cvt_k(const float* __restrict__ in, bf16* __restrict__ out,
                     int R, int Ccols) {
  __shared__ bf16 tile[32][33];
  int c0 = blockIdx.x * 32, r0 = blockIdx.y * 32;
  int tx = threadIdx.x, ty = threadIdx.y; // block (32,8)
#pragma unroll
  for (int i = 0; i < 4; ++i)
    tile[ty + i * 8][tx] = (bf16)in[(size_t)(r0 + ty + i * 8) * Ccols + c0 + tx];
  __syncthreads();
#pragma unroll
  for (int i = 0; i < 4; ++i)
    out[(size_t)(c0 + ty + i * 8) * R + r0 + tx] = tile[tx][ty + i * 8];
}

// -------------------------------------------------- 256x256 phased GEMM
// C = A * BT^T.  A [M,K] bf16, BT [N,K] bf16.  BK=64, 8 waves (2Mx4N),
// 128 KiB LDS double-buffer, st-swizzled (inverse-swz global source +
// swizzled ds_read), counted vmcnt, setprio MFMA clusters.
// Schedule per K-tile t (buf c=t&1, 1 barrier/phase):
//  ph1: read A03,B01,B23(t); stage Ah1(t+1)->buf(1-c); MFMA m0-3 x n0-1
//  ph2: stage Ah0(t+1)->buf(1-c);                      MFMA m0-3 x n2-3
//  ph3: read A47(t); stage Bh0(t+2)->buf(c);           MFMA m4-7 x n0-1
//  ph4: stage Bh1(t+2)->buf(c); vmcnt(4);              MFMA m4-7 x n2-3
// vmcnt(4) certifies tile t+1 fully landed (its newest half staged ph2)
// one barrier before tile t+1's ph1 reads. Region safety: every staged
// region's reads were consumed >=1 barrier before the stage issues.
template <bool CF32, bool SCATV>
__global__ __launch_bounds__(512, 2)
void gemm256_k(const bf16* __restrict__ A, const bf16* __restrict__ BT,
               void* __restrict__ Craw, bf16* __restrict__ Vt,
               int M, int N, int K, int ldc) {
  extern __shared__ bf16 lds[]; // 131072 B: buf c: A@c*32768, B@c*32768+16384 (elems)
  const int nK = K >> 6;

  // bijective XCD-aware swizzle (nwg % 8 == 0 for our shapes)
  const int nbx = gridDim.x;
  const int nwg = nbx * gridDim.y;
  const int orig = blockIdx.x + blockIdx.y * nbx;
  const int q8 = nwg >> 3;
  const int wgid = (orig & 7) * q8 + (orig >> 3);
  const size_t col0 = (size_t)(wgid % nbx) * 256;
  const size_t row0 = (size_t)(wgid / nbx) * 256;

  const int tid = threadIdx.x;
  const int w = tid >> 6, lane = tid & 63;
  const int qn = lane & 15, quad = lane >> 4;
  const int wm = w >> 2, wn = w & 3;

  // staging: per half-tile (128 rows x 64 cols), wave w covers rows
  // {i*64 + w*8 + rl8}, i=0,1; inverse-swizzled global column chunk.
  const int rl8 = lane >> 3;                      // 0..7
  const int scol = ((lane & 7) ^ rl8) << 3;       // swizzled col (elems)
  const size_t gOff = (size_t)(w * 8 + rl8) * K + scol;
  const int ldsW = w * 512;

  // read-side swizzle: element col offset for k-half k32
  const int csA0 = (quad * 8) ^ ((qn & 7) << 3);
  const int csA1 = (32 + quad * 8) ^ ((qn & 7) << 3);
  const int aBaseIdx = wm * 8192 + qn * 64;
  const int bBaseIdx = 16384 + (wn >> 1) * 8192 + ((wn & 1) * 64 + qn) * 64;

  f32x4 acc[8][4];
  f32x4 zero4 = {0.f, 0.f, 0.f, 0.f};
#pragma unroll
  for (int m = 0; m < 8; ++m)
#pragma unroll
    for (int n = 0; n < 4; ++n) acc[m][n] = zero4;

  auto stageA = [&](int c, int h, int t) {
    const bf16* g = A + (row0 + h * 128) * (size_t)K + (size_t)t * 64 + gOff;
    const bf16* l = lds + c * 32768 + h * 8192 + ldsW;
    load_lds16(g, l);
    load_lds16(g + (size_t)64 * K, l + 4096);
  };
  auto stageB = [&](int c, int h, int t) {
    const bf16* g = BT + (col0 + h * 128) * (size_t)K + (size_t)t * 64 + gOff;
    const bf16* l = lds + c * 32768 + 16384 + h * 8192 + ldsW;
    load_lds16(g, l);
    load_lds16(g + (size_t)64 * K, l + 4096);
  };

  // prologue: tile0 all 4 halves, then Bh0(1), Bh1(1) (FIFO order matters)
  stageA(0, 0, 0); stageA(0, 1, 0);
  stageB(0, 0, 0); stageB(0, 1, 0);
  if (nK > 1) { stageB(1, 0, 1); stageB(1, 1, 1); }
  asm volatile("s_waitcnt vmcnt(4)" ::: "memory"); // tile0 landed; Bh(1) in flight
  asm volatile("s_barrier" ::: "memory");

  for (int t = 0; t < nK; ++t) {
    const int c = t & 1, cn = c ^ 1;
    const int cE = c * 32768;

    // ---------------- ph1: read A03 + all B; stage Ah1(t+1); MFMA m0-3 x n0-1
    bf16x8 a0[4][2], b0[2][2], b1[2][2];
#pragma unroll
    for (int m = 0; m < 4; ++m) {
      a0[m][0] = *(const bf16x8*)&lds[cE + aBaseIdx + m * 1024 + csA0];
      a0[m][1] = *(const bf16x8*)&lds[cE + aBaseIdx + m * 1024 + csA1];
    }
#pragma unroll
    for (int n = 0; n < 2; ++n) {
      b0[n][0] = *(const bf16x8*)&lds[cE + bBaseIdx + n * 1024 + csA0];
      b0[n][1] = *(const bf16x8*)&lds[cE + bBaseIdx + n * 1024 + csA1];
      b1[n][0] = *(const bf16x8*)&lds[cE + bBaseIdx + (n + 2) * 1024 + csA0];
      b1[n][1] = *(const bf16x8*)&lds[cE + bBaseIdx + (n + 2) * 1024 + csA1];
    }
    if (t + 1 < nK) stageA(cn, 1, t + 1);
    __builtin_amdgcn_s_setprio(1);
#pragma unroll
    for (int m = 0; m < 4; ++m)
#pragma unroll
      for (int n = 0; n < 2; ++n) {
        acc[m][n] = __builtin_amdgcn_mfma_f32_16x16x32_bf16(a0[m][0], b0[n][0], acc[m][n], 0, 0, 0);
        acc[m][n] = __builtin_amdgcn_mfma_f32_16x16x32_bf16(a0[m][1], b0[n][1], acc[m][n], 0, 0, 0);
      }
    __builtin_amdgcn_s_setprio(0);
    asm volatile("s_barrier" ::: "memory");

    // ---------------- ph2: stage Ah0(t+1); MFMA m0-3 x n2-3
    if (t + 1 < nK) stageA(cn, 0, t + 1);
    __builtin_amdgcn_s_setprio(1);
#pragma unroll
    for (int m = 0; m < 4; ++m)
#pragma unroll
      for (int n = 0; n < 2; ++n) {
        acc[m][n + 2] = __builtin_amdgcn_mfma_f32_16x16x32_bf16(a0[m][0], b1[n][0], acc[m][n + 2], 0, 0, 0);
        acc[m][n + 2] = __builtin_amdgcn_mfma_f32_16x16x32_bf16(a0[m][1], b1[n][1], acc[m][n + 2], 0, 0, 0);
      }
    __builtin_amdgcn_s_setprio(0);
    asm volatile("s_barrier" ::: "memory");

    // ---------------- ph3: read A47; stage Bh0(t+2); MFMA m4-7 x n0-1
    bf16x8 a1[4][2];
#pragma unroll
    for (int m = 0; m < 4; ++m) {
      a1[m][0] = *(const bf16x8*)&lds[cE + aBaseIdx + (m + 4) * 1024 + csA0];
      a1[m][1] = *(const bf16x8*)&lds[cE + aBaseIdx + (m + 4) * 1024 + csA1];
    }
    if (t + 2 < nK) stageB(c, 0, t + 2);
    __builtin_amdgcn_s_setprio(1);
#pragma unroll
    for (int m = 0; m < 4; ++m)
#pragma unroll
      for (int n = 0; n < 2; ++n) {
        acc[m + 4][n] = __builtin_amdgcn_mfma_f32_16x16x32_bf16(a1[m][0], b0[n][0], acc[m + 4][n], 0, 0, 0);
        acc[m + 4][n] = __builtin_amdgcn_mfma_f32_16x16x32_bf16(a1[m][1], b0[n][1], acc[m + 4][n], 0, 0, 0);
      }
    __builtin_amdgcn_s_setprio(0);
    asm volatile("s_barrier" ::: "memory");

    // ---------------- ph4: stage Bh1(t+2); vmcnt; MFMA m4-7 x n2-3
    if (t + 2 < nK) {
      stageB(c, 1, t + 2);
      asm volatile("s_waitcnt vmcnt(4)" ::: "memory"); // tile t+1 fully landed
    } else {
      asm volatile("s_waitcnt vmcnt(0)" ::: "memory"); // tail: drain
    }
    __builtin_amdgcn_s_setprio(1);
#pragma unroll
    for (int m = 0; m < 4; ++m)
#pragma unroll
      for (int n = 0; n < 2; ++n) {
        acc[m + 4][n + 2] = __builtin_amdgcn_mfma_f32_16x16x32_bf16(a1[m][0], b1[n][0], acc[m + 4][n + 2], 0, 0, 0);
        acc[m + 4][n + 2] = __builtin_amdgcn_mfma_f32_16x16x32_bf16(a1[m][1], b1[n][1], acc[m + 4][n + 2], 0, 0, 0);
      }
    __builtin_amdgcn_s_setprio(0);
    asm volatile("s_barrier" ::: "memory");
  }

  // ---------------- epilogue: C write
  if (SCATV && (int)col0 >= QKC) {
#pragma unroll
    for (int m = 0; m < 8; ++m)
#pragma unroll
      for (int n = 0; n < 4; ++n)
#pragma unroll
        for (int rr = 0; rr < 4; ++rr) {
          int row = (int)row0 + wm * 128 + m * 16 + quad * 4 + rr;
          int bb = row >> 11, tt = row & (T - 1);
          int cv = (int)col0 + wn * 64 + n * 16 + qn - QKC;
          int hh = cv >> 7, d = cv & 127;
          Vt[((size_t)(bb * NH + hh) * HD + d) * T + tt] = (bf16)acc[m][n][rr];
        }
  } else {
#pragma unroll
    for (int m = 0; m < 8; ++m)
#pragma unroll
      for (int n = 0; n < 4; ++n)
#pragma unroll
        for (int rr = 0; rr < 4; ++rr) {
          size_t idx = (row0 + wm * 128 + m * 16 + quad * 4 + rr) * (size_t)ldc +
                       col0 + wn * 64 + n * 16 + qn;
          if (CF32) ((float*)Craw)[idx] = acc[m][n][rr];
          else      ((bf16*)Craw)[idx] = (bf16)acc[m][n][rr];
        }
  }
}

// -------------------------------------------------- flash attention
// qk: [B, T, 2C] bf16 (q | k). vt: [B,H,HD,T] bf16. y: [B,T,C] bf16.
// 512 threads = 8 waves; Q-tile 128 (16 rows/wave); K-tile 64.
// Swapped QK^T: St = mfma(K,Q) so each lane owns P[q=lane&15][16 k-vals].
// P never touches LDS (ds_bpermute redistribution to A-frag layout).
constexpr int KSTR = 136, VSTR = 72;

__global__ __launch_bounds__(512, 4)
void attn_k(const bf16* __restrict__ qk, const bf16* __restrict__ vt,
            bf16* __restrict__ y) {
  const int b = blockIdx.z, h = blockIdx.y;
  const int qb = (int)(gridDim.x - 1 - blockIdx.x); // heavy blocks first
  const int qt0 = qb * 128;
  const int tid = threadIdx.x;
  const int w = tid >> 6, lane = tid & 63;
  const int qn = lane & 15, quad = lane >> 4;
  const int q0 = qt0 + w * 16;

  __shared__ __align__(16) bf16 Ks[64 * KSTR];  // [key][hd], padded
  __shared__ __align__(16) bf16 Vs[128 * VSTR]; // [hd][key], padded

  const bf16* qkB = qk + (size_t)b * T * QKC + h * HD;
  const bf16* vtB = vt + (size_t)(b * NH + h) * HD * T;
  const bf16* kBase = qkB + Cdim; // k section

  // Q fragment (B-operand layout), pre-scaled by 1/sqrt(hd)
  bf16x8 qF[4];
  {
    const float scale = 0.088388347648318447f; // 1/sqrt(128)
    const bf16* qRow = qkB + (size_t)(q0 + qn) * QKC;
#pragma unroll
    for (int c = 0; c < 4; ++c) {
      bf16x8 v = *(const bf16x8*)(qRow + c * 32 + quad * 8);
#pragma unroll
      for (int j = 0; j < 8; ++j) v[j] = (bf16)((float)v[j] * scale);
      qF[c] = v;
    }
  }

  float m_i = NEG_BIG, l_i = 0.f;
  f32x4 zero4 = {0.f, 0.f, 0.f, 0.f};
  f32x4 o[8];
#pragma unroll
  for (int cc = 0; cc < 8; ++cc) o[cc] = zero4;

  const int kr  = tid >> 4;        // 0..31
  const int kc8 = (tid & 15) << 3; // 0..120
  const int vd  = tid >> 3;        // 0..63
  const int vk8 = (tid & 7) << 3;  // 0..56

  // bpermute byte addresses for P redistribution (cross-quad, same qn)
  const int addrA = ((lane & 15) + ((quad & 1) << 5)) << 2; // src quad (quad&1)*2
  const int addrB = addrA + 64;                             // src quad (quad&1)*2+1

  const int nT = 2 * qb + 2;

  // prologue: issue global loads for tile 0 (async-stage split, T14)
  bf16x8 rK0 = *(const bf16x8*)(kBase + (size_t)kr * QKC + kc8);
  bf16x8 rK1 = *(const bf16x8*)(kBase + (size_t)(kr + 32) * QKC + kc8);
  bf16x8 rV0 = *(const bf16x8*)(vtB + (size_t)vd * T + vk8);
  bf16x8 rV1 = *(const bf16x8*)(vtB + (size_t)(vd + 64) * T + vk8);

  for (int t = 0; t < nT; ++t) {
    const int kt0 = t * 64;
    __syncthreads(); // prev tile's LDS reads done
    *(bf16x8*)&Ks[kr * KSTR + kc8] = rK0;
    *(bf16x8*)&Ks[(kr + 32) * KSTR + kc8] = rK1;
    *(bf16x8*)&Vs[vd * VSTR + vk8] = rV0;
    *(bf16x8*)&Vs[(vd + 64) * VSTR + vk8] = rV1;
    __syncthreads(); // LDS tile ready
    if (t + 1 < nT) { // issue next tile's loads; latency hides under compute
      const int kn = kt0 + 64;
      rK0 = *(const bf16x8*)(kBase + (size_t)(kn + kr) * QKC + kc8);
      rK1 = *(const bf16x8*)(kBase + (size_t)(kn + kr + 32) * QKC + kc8);
      rV0 = *(const bf16x8*)(vtB + (size_t)vd * T + kn + vk8);
      rV1 = *(const bf16x8*)(vtB + (size_t)(vd + 64) * T + kn + vk8);
    }
    if (kt0 > q0 + 15) continue; // wave-uniform; barriers already passed

    // ---- St = K Q^T (swapped): s[ks][rr] = S[q0+qn][kt0+ks*16+quad*4+rr]
    f32x4 s[4] = {zero4, zero4, zero4, zero4};
    __builtin_amdgcn_s_setprio(1);
#pragma unroll
    for (int c = 0; c < 4; ++c)
#pragma unroll
      for (int ks = 0; ks < 4; ++ks) {
        bf16x8 kf = *(const bf16x8*)&Ks[(ks * 16 + qn) * KSTR + c * 32 + quad * 8];
        s[ks] = __builtin_amdgcn_mfma_f32_16x16x32_bf16(kf, qF[c], s[ks], 0, 0, 0);
      }
    __builtin_amdgcn_s_setprio(0);

    // ---- causal mask (active waves have kt0 <= q0, never fully-masked rows)
    if (kt0 + 63 > q0) {
      const int qv = q0 + qn;
#pragma unroll
      for (int ks = 0; ks < 4; ++ks)
#pragma unroll
        for (int rr = 0; rr < 4; ++rr)
          if (kt0 + ks * 16 + quad * 4 + rr > qv) s[ks][rr] = NEG_BIG;
    }

    // ---- tile max: 15 local + 2 shuffles (k is quad-split per qn)
    float mx = s[0][0];
#pragma unroll
    for (int ks = 0; ks < 4; ++ks)
#pragma unroll
      for (int rr = 0; rr < 4; ++rr) mx = fmaxf(mx, s[ks][rr]);
    mx = fmaxf(mx, __shfl_xor(mx, 16));
    mx = fmaxf(mx, __shfl_xor(mx, 32));

    // ---- defer-max rescale (T13): only when max actually grows past THR
    if (!__all(mx - m_i <= 8.0f)) {
      float mn = fmaxf(m_i, mx);
      float alpha = __expf(m_i - mn);
      m_i = mn;
      l_i *= alpha;
      float aR[4];
#pragma unroll
      for (int rr = 0; rr < 4; ++rr) aR[rr] = __shfl(alpha, quad * 4 + rr);
#pragma unroll
      for (int cc = 0; cc < 8; ++cc)
#pragma unroll
        for (int rr = 0; rr < 4; ++rr) o[cc][rr] *= aR[rr];
    }

    // ---- P = exp(S - m), row-sum (in place)
    float rs = 0.f;
#pragma unroll
    for (int ks = 0; ks < 4; ++ks)
#pragma unroll
      for (int rr = 0; rr < 4; ++rr) {
        float pv = __expf(s[ks][rr] - m_i);
        s[ks][rr] = pv;
        rs += pv;
      }
    rs += __shfl_xor(rs, 16);
    rs += __shfl_xor(rs, 32);
    l_i += rs;

    // ---- pack P to bf16 pairs: pku[ks][b] = (P[k=ks*16+quad*4+2b], +1)
    uint32_t pku[4][2];
#pragma unroll
    for (int ks = 0; ks < 4; ++ks)
#pragma unroll
      for (int b2 = 0; b2 < 2; ++b2)
        pku[ks][b2] = pack2bf(s[ks][2 * b2], s[ks][2 * b2 + 1]);

    // ---- redistribute to A-frag layout: pa[c][j] = P[qn][c*32+quad*8+j]
    // src lane = qn + 16*((quad&1)*2 + (j>>2)); src reg ks = 2c + (quad>>1)
    const int hi2 = quad >> 1;
    __builtin_amdgcn_s_setprio(1);
#pragma unroll
    for (int c = 0; c < 2; ++c) {
      uint32_t lo0A = (uint32_t)__builtin_amdgcn_ds_bpermute(addrA, (int)pku[2 * c][0]);
      uint32_t lo1A = (uint32_t)__builtin_amdgcn_ds_bpermute(addrA, (int)pku[2 * c][1]);
      uint32_t lo0B = (uint32_t)__builtin_amdgcn_ds_bpermute(addrB, (int)pku[2 * c][0]);
      uint32_t lo1B = (uint32_t)__builtin_amdgcn_ds_bpermute(addrB, (int)pku[2 * c][1]);
      uint32_t hi0A = (uint32_t)__builtin_amdgcn_ds_bpermute(addrA, (int)pku[2 * c + 1][0]);
      uint32_t hi1A = (uint32_t)__builtin_amdgcn_ds_bpermute(addrA, (int)pku[2 * c + 1][1]);
      uint32_t hi0B = (uint32_t)__builtin_amdgcn_ds_bpermute(addrB, (int)pku[2 * c + 1][0]);
      uint32_t hi1B = (uint32_t)__builtin_amdgcn_ds_bpermute(addrB, (int)pku[2 * c + 1][1]);
      u32x4 pw;
      pw[0] = hi2 ? hi0A : lo0A; // j=0,1
      pw[1] = hi2 ? hi1A : lo1A; // j=2,3
      pw[2] = hi2 ? hi0B : lo0B; // j=4,5
      pw[3] = hi2 ? hi1B : lo1B; // j=6,7
      bf16x8 pF = __builtin_bit_cast(bf16x8, pw);
#pragma unroll
      for (int cc = 0; cc < 8; ++cc) {
        bf16x8 vf = *(const bf16x8*)&Vs[(cc * 16 + qn) * VSTR + c * 32 + quad * 8];
        o[cc] = __builtin_amdgcn_mfma_f32_16x16x32_bf16(pF, vf, o[cc], 0, 0, 0);
      }
    }
    __builtin_amdgcn_s_setprio(0);
  }

  // ---- epilogue: broadcast l to O's row layout (q = quad*4+rr)
  float linv[4];
#pragma unroll
  for (int rr = 0; rr < 4; ++rr) {
    float lr = __shfl(l_i, quad * 4 + rr);
    linv[rr] = 1.f / fmaxf(lr, 1e-30f);
  }
  bf16* yB = y + (size_t)b * T * Cdim + h * HD;
#pragma unroll
  for (int cc = 0; cc < 8; ++cc)
#pragma unroll
    for (int rr = 0; rr < 4; ++rr)
      yB[(size_t)(q0 + quad * 4 + rr) * Cdim + cc * 16 + qn] =
          (bf16)(o[cc][rr] * linv[rr]);
}

// -------------------------------------------------- launch
extern "C" void kernel_launch(void* const* d_in, const int* in_sizes, int n_in,
                              void* d_out, int out_size, void* d_ws, size_t ws_size,
                              hipStream_t stream) {
  const float* x     = (const float*)d_in[0]; // [4,2048,2048] fp32
  const float* Wqkv  = (const float*)d_in[1]; // [2048,6144]  fp32
  const float* Wproj = (const float*)d_in[2]; // [2048,2048]  fp32
  float* out = (float*)d_out;                 // [4,2048,2048] fp32

  char* ws = (char*)d_ws;
  // ws: [0,64M) qk bf16. [64M,96M) Vt bf16. [96M,120M) WqkvT (dead after
  // gemm1) / y bf16 aliases [96M,128M). [128M,136M) WprojT. Total 136 MiB.
  // xb (bf16 copy of x, 32MB) lives in d_out, which is dead until gemm2
  // fully overwrites it.
  bf16* qkbuf  = (bf16*)(ws);
  bf16* Vt     = (bf16*)(ws + (size_t)64 * 1024 * 1024);
  bf16* WqkvT  = (bf16*)(ws + (size_t)96 * 1024 * 1024);
  bf16* y      = WqkvT; // alias, sequenced
  bf16* WprojT = (bf16*)(ws + (size_t)128 * 1024 * 1024);
  bf16* xb     = (bf16*)d_out; // scratch until gemm2 overwrites

  cvt_bf16_k<<<dim3((Bz * T * Cdim) / (256 * 8)), 256, 0, stream>>>(x, xb);
  transpose_cvt_k<<<dim3(QKVC / 32, Cdim / 32), dim3(32, 8), 0, stream>>>(
      Wqkv, WqkvT, Cdim, QKVC);
  transpose_cvt_k<<<dim3(Cdim / 32, Cdim / 32), dim3(32, 8), 0, stream>>>(
      Wproj, WprojT, Cdim, Cdim);

  // qkv GEMM: q,k -> qkbuf; v -> Vt (scattered transposed)
  gemm256_k<false, true><<<dim3(QKVC / 256, (Bz * T) / 256), 512, 131072, stream>>>(
      xb, WqkvT, (void*)qkbuf, Vt, Bz * T, QKVC, Cdim, QKC);

  // causal flash attention
  attn_k<<<dim3(T / 128, NH, Bz), 512, 0, stream>>>(qkbuf, Vt, y);

  // out = y @ Wproj
  gemm256_k<true, false><<<dim3(Cdim / 256, (Bz * T) / 256), 512, 131072, stream>>>(
      y, WprojT, (void*)out, nullptr, Bz * T, Cdim, Cdim, Cdim);
}

// Round 3
// 550.276 us; speedup vs baseline: 1.5074x; 1.0972x over previous
//
#include <hip/hip_runtime.h>
#include <hip/hip_bf16.h>
#include <cstdint>

typedef __bf16 bf16;
typedef __bf16 bf16x8 __attribute__((ext_vector_type(8)));
typedef float f32x4 __attribute__((ext_vector_type(4)));
typedef float f32x8 __attribute__((ext_vector_type(8)));
typedef uint32_t u32x4 __attribute__((ext_vector_type(4)));

constexpr int Bz = 4, T = 2048, Cdim = 2048, NH = 16, HD = 128;
constexpr int QKVC = 3 * Cdim; // 6144
constexpr int QKC = 2 * Cdim;  // 4096 (q|k buffer row stride)
constexpr float NEG_BIG = -3.0e4f;

// async global->LDS, 16B per lane; l must be the WAVE-UNIFORM base
__device__ __forceinline__ void load_lds16(const bf16* g, const bf16* l) {
  __builtin_amdgcn_global_load_lds(
      (const __attribute__((address_space(1))) void*)g,
      (__attribute__((address_space(3))) void*)l, 16, 0, 0);
}

__device__ __forceinline__ uint32_t pack2bf(float lo, float hi) {
  uint16_t a = __builtin_bit_cast(uint16_t, (bf16)lo);
  uint16_t b = __builtin_bit_cast(uint16_t, (bf16)hi);
  return ((uint32_t)b << 16) | (uint32_t)a;
}

// -------------------------------------------------- fp32 -> bf16 convert
__global__ __launch_bounds__(256)
void cvt_bf16_k(const float* __restrict__ in, bf16* __restrict__ out) {
  size_t i = (size_t)blockIdx.x * 256 + threadIdx.x;
  f32x8 v = *(const f32x8*)(in + i * 8);
  bf16x8 h;
#pragma unroll
  for (int j = 0; j < 8; ++j) h[j] = (bf16)v[j];
  *(bf16x8*)(out + i * 8) = h;
}

// -------------------------------------------------- fp32 -> bf16 transpose
__global__ __launch_bounds__(256)
void transpose_cvt_k(const float* __restrict__ in, bf16* __restrict__ out,
                     int R, int Ccols) {
  __shared__ bf16 tile[32][33];
  int c0 = blockIdx.x * 32, r0 = blockIdx.y * 32;
  int tx = threadIdx.x, ty = threadIdx.y; // block (32,8)
#pragma unroll
  for (int i = 0; i < 4; ++i)
    tile[ty + i * 8][tx] = (bf16)in[(size_t)(r0 + ty + i * 8) * Ccols + c0 + tx];
  __syncthreads();
#pragma unroll
  for (int i = 0; i < 4; ++i)
    out[(size_t)(c0 + ty + i * 8) * R + r0 + tx] = tile[tx][ty + i * 8];
}

// -------------------------------------------------- 256x256 phased GEMM
// (unchanged from previous round — see schedule comment)
template <bool CF32, bool SCATV>
__global__ __launch_bounds__(512, 2)
void gemm256_k(const bf16* __restrict__ A, const bf16* __restrict__ BT,
               void* __restrict__ Craw, bf16* __restrict__ Vt,
               int M, int N, int K, int ldc) {
  extern __shared__ bf16 lds[]; // 131072 B
  const int nK = K >> 6;

  const int nbx = gridDim.x;
  const int nwg = nbx * gridDim.y;
  const int orig = blockIdx.x + blockIdx.y * nbx;
  const int q8 = nwg >> 3;
  const int wgid = (orig & 7) * q8 + (orig >> 3);
  const size_t col0 = (size_t)(wgid % nbx) * 256;
  const size_t row0 = (size_t)(wgid / nbx) * 256;

  const int tid = threadIdx.x;
  const int w = tid >> 6, lane = tid & 63;
  const int qn = lane & 15, quad = lane >> 4;
  const int wm = w >> 2, wn = w & 3;

  const int rl8 = lane >> 3;
  const int scol = ((lane & 7) ^ rl8) << 3;
  const size_t gOff = (size_t)(w * 8 + rl8) * K + scol;
  const int ldsW = w * 512;

  const int csA0 = (quad * 8) ^ ((qn & 7) << 3);
  const int csA1 = (32 + quad * 8) ^ ((qn & 7) << 3);
  const int aBaseIdx = wm * 8192 + qn * 64;
  const int bBaseIdx = 16384 + (wn >> 1) * 8192 + ((wn & 1) * 64 + qn) * 64;

  f32x4 acc[8][4];
  f32x4 zero4 = {0.f, 0.f, 0.f, 0.f};
#pragma unroll
  for (int m = 0; m < 8; ++m)
#pragma unroll
    for (int n = 0; n < 4; ++n) acc[m][n] = zero4;

  auto stageA = [&](int c, int h, int t) {
    const bf16* g = A + (row0 + h * 128) * (size_t)K + (size_t)t * 64 + gOff;
    const bf16* l = lds + c * 32768 + h * 8192 + ldsW;
    load_lds16(g, l);
    load_lds16(g + (size_t)64 * K, l + 4096);
  };
  auto stageB = [&](int c, int h, int t) {
    const bf16* g = BT + (col0 + h * 128) * (size_t)K + (size_t)t * 64 + gOff;
    const bf16* l = lds + c * 32768 + 16384 + h * 8192 + ldsW;
    load_lds16(g, l);
    load_lds16(g + (size_t)64 * K, l + 4096);
  };

  stageA(0, 0, 0); stageA(0, 1, 0);
  stageB(0, 0, 0); stageB(0, 1, 0);
  if (nK > 1) { stageB(1, 0, 1); stageB(1, 1, 1); }
  asm volatile("s_waitcnt vmcnt(4)" ::: "memory");
  asm volatile("s_barrier" ::: "memory");

  for (int t = 0; t < nK; ++t) {
    const int c = t & 1, cn = c ^ 1;
    const int cE = c * 32768;

    bf16x8 a0[4][2], b0[2][2], b1[2][2];
#pragma unroll
    for (int m = 0; m < 4; ++m) {
      a0[m][0] = *(const bf16x8*)&lds[cE + aBaseIdx + m * 1024 + csA0];
      a0[m][1] = *(const bf16x8*)&lds[cE + aBaseIdx + m * 1024 + csA1];
    }
#pragma unroll
    for (int n = 0; n < 2; ++n) {
      b0[n][0] = *(const bf16x8*)&lds[cE + bBaseIdx + n * 1024 + csA0];
      b0[n][1] = *(const bf16x8*)&lds[cE + bBaseIdx + n * 1024 + csA1];
      b1[n][0] = *(const bf16x8*)&lds[cE + bBaseIdx + (n + 2) * 1024 + csA0];
      b1[n][1] = *(const bf16x8*)&lds[cE + bBaseIdx + (n + 2) * 1024 + csA1];
    }
    if (t + 1 < nK) stageA(cn, 1, t + 1);
    __builtin_amdgcn_s_setprio(1);
#pragma unroll
    for (int m = 0; m < 4; ++m)
#pragma unroll
      for (int n = 0; n < 2; ++n) {
        acc[m][n] = __builtin_amdgcn_mfma_f32_16x16x32_bf16(a0[m][0], b0[n][0], acc[m][n], 0, 0, 0);
        acc[m][n] = __builtin_amdgcn_mfma_f32_16x16x32_bf16(a0[m][1], b0[n][1], acc[m][n], 0, 0, 0);
      }
    __builtin_amdgcn_s_setprio(0);
    asm volatile("s_barrier" ::: "memory");

    if (t + 1 < nK) stageA(cn, 0, t + 1);
    __builtin_amdgcn_s_setprio(1);
#pragma unroll
    for (int m = 0; m < 4; ++m)
#pragma unroll
      for (int n = 0; n < 2; ++n) {
        acc[m][n + 2] = __builtin_amdgcn_mfma_f32_16x16x32_bf16(a0[m][0], b1[n][0], acc[m][n + 2], 0, 0, 0);
        acc[m][n + 2] = __builtin_amdgcn_mfma_f32_16x16x32_bf16(a0[m][1], b1[n][1], acc[m][n + 2], 0, 0, 0);
      }
    __builtin_amdgcn_s_setprio(0);
    asm volatile("s_barrier" ::: "memory");

    bf16x8 a1[4][2];
#pragma unroll
    for (int m = 0; m < 4; ++m) {
      a1[m][0] = *(const bf16x8*)&lds[cE + aBaseIdx + (m + 4) * 1024 + csA0];
      a1[m][1] = *(const bf16x8*)&lds[cE + aBaseIdx + (m + 4) * 1024 + csA1];
    }
    if (t + 2 < nK) stageB(c, 0, t + 2);
    __builtin_amdgcn_s_setprio(1);
#pragma unroll
    for (int m = 0; m < 4; ++m)
#pragma unroll
      for (int n = 0; n < 2; ++n) {
        acc[m + 4][n] = __builtin_amdgcn_mfma_f32_16x16x32_bf16(a1[m][0], b0[n][0], acc[m + 4][n], 0, 0, 0);
        acc[m + 4][n] = __builtin_amdgcn_mfma_f32_16x16x32_bf16(a1[m][1], b0[n][1], acc[m + 4][n], 0, 0, 0);
      }
    __builtin_amdgcn_s_setprio(0);
    asm volatile("s_barrier" ::: "memory");

    if (t + 2 < nK) {
      stageB(c, 1, t + 2);
      asm volatile("s_waitcnt vmcnt(4)" ::: "memory");
    } else {
      asm volatile("s_waitcnt vmcnt(0)" ::: "memory");
    }
    __builtin_amdgcn_s_setprio(1);
#pragma unroll
    for (int m = 0; m < 4; ++m)
#pragma unroll
      for (int n = 0; n < 2; ++n) {
        acc[m + 4][n + 2] = __builtin_amdgcn_mfma_f32_16x16x32_bf16(a1[m][0], b1[n][0], acc[m + 4][n + 2], 0, 0, 0);
        acc[m + 4][n + 2] = __builtin_amdgcn_mfma_f32_16x16x32_bf16(a1[m][1], b1[n][1], acc[m + 4][n + 2], 0, 0, 0);
      }
    __builtin_amdgcn_s_setprio(0);
    asm volatile("s_barrier" ::: "memory");
  }

  if (SCATV && (int)col0 >= QKC) {
#pragma unroll
    for (int m = 0; m < 8; ++m)
#pragma unroll
      for (int n = 0; n < 4; ++n)
#pragma unroll
        for (int rr = 0; rr < 4; ++rr) {
          int row = (int)row0 + wm * 128 + m * 16 + quad * 4 + rr;
          int bb = row >> 11, tt = row & (T - 1);
          int cv = (int)col0 + wn * 64 + n * 16 + qn - QKC;
          int hh = cv >> 7, d = cv & 127;
          Vt[((size_t)(bb * NH + hh) * HD + d) * T + tt] = (bf16)acc[m][n][rr];
        }
  } else {
#pragma unroll
    for (int m = 0; m < 8; ++m)
#pragma unroll
      for (int n = 0; n < 4; ++n)
#pragma unroll
        for (int rr = 0; rr < 4; ++rr) {
          size_t idx = (row0 + wm * 128 + m * 16 + quad * 4 + rr) * (size_t)ldc +
                       col0 + wn * 64 + n * 16 + qn;
          if (CF32) ((float*)Craw)[idx] = acc[m][n][rr];
          else      ((bf16*)Craw)[idx] = (bf16)acc[m][n][rr];
        }
  }
}

// -------------------------------------------------- flash attention
// qk: [B, T, 2C] bf16 (q | k). vt: [B,H,HD,T] bf16. y: [B,T,C] bf16.
// 512 threads = 8 waves. PAIRED q-tiles (qbA = x, qbB = 15-x): every block
// does exactly 34 tile-units (perfect causal load balance), and each wave
// carries two independent 16-row Q parts through the shared K/V tiles so
// one K/V fragment read feeds 2 MFMAs. Swapped QK^T; P stays in registers
// (ds_bpermute redistribution). Note actA => actB structurally.
constexpr int KSTR = 136, VSTR = 72;

__global__ __launch_bounds__(512, 2)
void attn_k(const bf16* __restrict__ qk, const bf16* __restrict__ vt,
            bf16* __restrict__ y) {
  const int b = blockIdx.z, h = blockIdx.y;
  const int qbA = blockIdx.x;      // 0..7  (light part)
  const int qbB = 15 - qbA;        // 8..15 (heavy part)
  const int tid = threadIdx.x;
  const int w = tid >> 6, lane = tid & 63;
  const int qn = lane & 15, quad = lane >> 4;
  const int q0A = qbA * 128 + w * 16;
  const int q0B = qbB * 128 + w * 16;

  __shared__ __align__(16) bf16 Ks[64 * KSTR];  // [key][hd], padded
  __shared__ __align__(16) bf16 Vs[128 * VSTR]; // [hd][key], padded

  const bf16* qkB = qk + (size_t)b * T * QKC + h * HD;
  const bf16* vtB = vt + (size_t)(b * NH + h) * HD * T;
  const bf16* kBase = qkB + Cdim; // k section

  // Q fragments (B-operand layout), pre-scaled by 1/sqrt(hd)
  bf16x8 qFA[4], qFB[4];
  {
    const float scale = 0.088388347648318447f; // 1/sqrt(128)
    const bf16* qRowA = qkB + (size_t)(q0A + qn) * QKC;
    const bf16* qRowB = qkB + (size_t)(q0B + qn) * QKC;
#pragma unroll
    for (int c = 0; c < 4; ++c) {
      bf16x8 va = *(const bf16x8*)(qRowA + c * 32 + quad * 8);
      bf16x8 vb = *(const bf16x8*)(qRowB + c * 32 + quad * 8);
#pragma unroll
      for (int j = 0; j < 8; ++j) {
        va[j] = (bf16)((float)va[j] * scale);
        vb[j] = (bf16)((float)vb[j] * scale);
      }
      qFA[c] = va; qFB[c] = vb;
    }
  }

  float mA = NEG_BIG, lA = 0.f, mB = NEG_BIG, lB = 0.f;
  f32x4 zero4 = {0.f, 0.f, 0.f, 0.f};
  f32x4 oA[8], oB[8];
#pragma unroll
  for (int cc = 0; cc < 8; ++cc) { oA[cc] = zero4; oB[cc] = zero4; }

  const int kr  = tid >> 4;        // 0..31
  const int kc8 = (tid & 15) << 3; // 0..120
  const int vd  = tid >> 3;        // 0..63
  const int vk8 = (tid & 7) << 3;  // 0..56

  // bpermute byte addresses for P redistribution (cross-quad, same qn)
  const int addrA = ((lane & 15) + ((quad & 1) << 5)) << 2;
  const int addrB = addrA + 64;
  const int hi2 = quad >> 1;

  // softmax + pack for one part (mask, online max w/ defer-rescale, exp+sum)
  auto softmax_pack = [&](f32x4 (&s)[4], int q0p, int kt0, float& m_i,
                          float& l_i, f32x4 (&o)[8], uint32_t (&pku)[4][2]) {
    if (kt0 + 63 > q0p) {
      const int qv = q0p + qn;
#pragma unroll
      for (int ks = 0; ks < 4; ++ks)
#pragma unroll
        for (int rr = 0; rr < 4; ++rr)
          if (kt0 + ks * 16 + quad * 4 + rr > qv) s[ks][rr] = NEG_BIG;
    }
    float mx = s[0][0];
#pragma unroll
    for (int ks = 0; ks < 4; ++ks)
#pragma unroll
      for (int rr = 0; rr < 4; ++rr) mx = fmaxf(mx, s[ks][rr]);
    mx = fmaxf(mx, __shfl_xor(mx, 16));
    mx = fmaxf(mx, __shfl_xor(mx, 32));
    if (!__all(mx - m_i <= 8.0f)) {
      float mn = fmaxf(m_i, mx);
      float alpha = __expf(m_i - mn);
      m_i = mn;
      l_i *= alpha;
      float aR[4];
#pragma unroll
      for (int rr = 0; rr < 4; ++rr) aR[rr] = __shfl(alpha, quad * 4 + rr);
#pragma unroll
      for (int cc = 0; cc < 8; ++cc)
#pragma unroll
        for (int rr = 0; rr < 4; ++rr) o[cc][rr] *= aR[rr];
    }
    float rs = 0.f;
#pragma unroll
    for (int ks = 0; ks < 4; ++ks)
#pragma unroll
      for (int rr = 0; rr < 4; ++rr) {
        float pv = __expf(s[ks][rr] - m_i);
        s[ks][rr] = pv;
        rs += pv;
      }
    rs += __shfl_xor(rs, 16);
    rs += __shfl_xor(rs, 32);
    l_i += rs;
#pragma unroll
    for (int ks = 0; ks < 4; ++ks)
#pragma unroll
      for (int b2 = 0; b2 < 2; ++b2)
        pku[ks][b2] = pack2bf(s[ks][2 * b2], s[ks][2 * b2 + 1]);
  };

  // P redistribution to A-frag layout: pa[c][j] = P[qn][c*32+quad*8+j]
  auto redist = [&](uint32_t (&pku)[4][2], int c) -> bf16x8 {
    uint32_t lo0A = (uint32_t)__builtin_amdgcn_ds_bpermute(addrA, (int)pku[2 * c][0]);
    uint32_t lo1A = (uint32_t)__builtin_amdgcn_ds_bpermute(addrA, (int)pku[2 * c][1]);
    uint32_t lo0B = (uint32_t)__builtin_amdgcn_ds_bpermute(addrB, (int)pku[2 * c][0]);
    uint32_t lo1B = (uint32_t)__builtin_amdgcn_ds_bpermute(addrB, (int)pku[2 * c][1]);
    uint32_t hi0A = (uint32_t)__builtin_amdgcn_ds_bpermute(addrA, (int)pku[2 * c + 1][0]);
    uint32_t hi1A = (uint32_t)__builtin_amdgcn_ds_bpermute(addrA, (int)pku[2 * c + 1][1]);
    uint32_t hi0B = (uint32_t)__builtin_amdgcn_ds_bpermute(addrB, (int)pku[2 * c + 1][0]);
    uint32_t hi1B = (uint32_t)__builtin_amdgcn_ds_bpermute(addrB, (int)pku[2 * c + 1][1]);
    u32x4 pw;
    pw[0] = hi2 ? hi0A : lo0A;
    pw[1] = hi2 ? hi1A : lo1A;
    pw[2] = hi2 ? hi0B : lo0B;
    pw[3] = hi2 ? hi1B : lo1B;
    return __builtin_bit_cast(bf16x8, pw);
  };

  const int nT = 2 * qbB + 2;

  // prologue: issue global loads for tile 0 (async-stage split, T14)
  bf16x8 rK0 = *(const bf16x8*)(kBase + (size_t)kr * QKC + kc8);
  bf16x8 rK1 = *(const bf16x8*)(kBase + (size_t)(kr + 32) * QKC + kc8);
  bf16x8 rV0 = *(const bf16x8*)(vtB + (size_t)vd * T + vk8);
  bf16x8 rV1 = *(const bf16x8*)(vtB + (size_t)(vd + 64) * T + vk8);

  for (int t = 0; t < nT; ++t) {
    const int kt0 = t * 64;
    __syncthreads(); // prev tile's LDS reads done
    *(bf16x8*)&Ks[kr * KSTR + kc8] = rK0;
    *(bf16x8*)&Ks[(kr + 32) * KSTR + kc8] = rK1;
    *(bf16x8*)&Vs[vd * VSTR + vk8] = rV0;
    *(bf16x8*)&Vs[(vd + 64) * VSTR + vk8] = rV1;
    __syncthreads(); // LDS tile ready
    if (t + 1 < nT) { // issue next tile's loads; latency hides under compute
      const int kn = kt0 + 64;
      rK0 = *(const bf16x8*)(kBase + (size_t)(kn + kr) * QKC + kc8);
      rK1 = *(const bf16x8*)(kBase + (size_t)(kn + kr + 32) * QKC + kc8);
      rV0 = *(const bf16x8*)(vtB + (size_t)vd * T + kn + vk8);
      rV1 = *(const bf16x8*)(vtB + (size_t)(vd + 64) * T + kn + vk8);
    }
    const bool actA = (kt0 <= q0A + 15);
    const bool actB = (kt0 <= q0B + 15);
    if (!actB) continue; // implies !actA; barriers already passed

    // ---- St = K Q^T (swapped); shared kf feeds both parts
    f32x4 sA[4] = {zero4, zero4, zero4, zero4};
    f32x4 sB[4] = {zero4, zero4, zero4, zero4};
    __builtin_amdgcn_s_setprio(1);
    if (actA) {
#pragma unroll
      for (int c = 0; c < 4; ++c)
#pragma unroll
        for (int ks = 0; ks < 4; ++ks) {
          bf16x8 kf = *(const bf16x8*)&Ks[(ks * 16 + qn) * KSTR + c * 32 + quad * 8];
          sA[ks] = __builtin_amdgcn_mfma_f32_16x16x32_bf16(kf, qFA[c], sA[ks], 0, 0, 0);
          sB[ks] = __builtin_amdgcn_mfma_f32_16x16x32_bf16(kf, qFB[c], sB[ks], 0, 0, 0);
        }
    } else {
#pragma unroll
      for (int c = 0; c < 4; ++c)
#pragma unroll
        for (int ks = 0; ks < 4; ++ks) {
          bf16x8 kf = *(const bf16x8*)&Ks[(ks * 16 + qn) * KSTR + c * 32 + quad * 8];
          sB[ks] = __builtin_amdgcn_mfma_f32_16x16x32_bf16(kf, qFB[c], sB[ks], 0, 0, 0);
        }
    }
    __builtin_amdgcn_s_setprio(0);

    uint32_t pkuA[4][2], pkuB[4][2];
    if (actA) softmax_pack(sA, q0A, kt0, mA, lA, oA, pkuA);
    softmax_pack(sB, q0B, kt0, mB, lB, oB, pkuB);

    // ---- PV: shared vf feeds both parts
    __builtin_amdgcn_s_setprio(1);
    if (actA) {
#pragma unroll
      for (int c = 0; c < 2; ++c) {
        bf16x8 pFA = redist(pkuA, c);
        bf16x8 pFB = redist(pkuB, c);
#pragma unroll
        for (int cc = 0; cc < 8; ++cc) {
          bf16x8 vf = *(const bf16x8*)&Vs[(cc * 16 + qn) * VSTR + c * 32 + quad * 8];
          oA[cc] = __builtin_amdgcn_mfma_f32_16x16x32_bf16(pFA, vf, oA[cc], 0, 0, 0);
          oB[cc] = __builtin_amdgcn_mfma_f32_16x16x32_bf16(pFB, vf, oB[cc], 0, 0, 0);
        }
      }
    } else {
#pragma unroll
      for (int c = 0; c < 2; ++c) {
        bf16x8 pFB = redist(pkuB, c);
#pragma unroll
        for (int cc = 0; cc < 8; ++cc) {
          bf16x8 vf = *(const bf16x8*)&Vs[(cc * 16 + qn) * VSTR + c * 32 + quad * 8];
          oB[cc] = __builtin_amdgcn_mfma_f32_16x16x32_bf16(pFB, vf, oB[cc], 0, 0, 0);
        }
      }
    }
    __builtin_amdgcn_s_setprio(0);
  }

  // ---- epilogue: both parts; broadcast l to O's row layout (q = quad*4+rr)
  bf16* yB = y + (size_t)b * T * Cdim + h * HD;
  {
    float linv[4];
#pragma unroll
    for (int rr = 0; rr < 4; ++rr) {
      float lr = __shfl(lA, quad * 4 + rr);
      linv[rr] = 1.f / fmaxf(lr, 1e-30f);
    }
#pragma unroll
    for (int cc = 0; cc < 8; ++cc)
#pragma unroll
      for (int rr = 0; rr < 4; ++rr)
        yB[(size_t)(q0A + quad * 4 + rr) * Cdim + cc * 16 + qn] =
            (bf16)(oA[cc][rr] * linv[rr]);
  }
  {
    float linv[4];
#pragma unroll
    for (int rr = 0; rr < 4; ++rr) {
      float lr = __shfl(lB, quad * 4 + rr);
      linv[rr] = 1.f / fmaxf(lr, 1e-30f);
    }
#pragma unroll
    for (int cc = 0; cc < 8; ++cc)
#pragma unroll
      for (int rr = 0; rr < 4; ++rr)
        yB[(size_t)(q0B + quad * 4 + rr) * Cdim + cc * 16 + qn] =
            (bf16)(oB[cc][rr] * linv[rr]);
  }
}

// -------------------------------------------------- launch
extern "C" void kernel_launch(void* const* d_in, const int* in_sizes, int n_in,
                              void* d_out, int out_size, void* d_ws, size_t ws_size,
                              hipStream_t stream) {
  const float* x     = (const float*)d_in[0]; // [4,2048,2048] fp32
  const float* Wqkv  = (const float*)d_in[1]; // [2048,6144]  fp32
  const float* Wproj = (const float*)d_in[2]; // [2048,2048]  fp32
  float* out = (float*)d_out;                 // [4,2048,2048] fp32

  char* ws = (char*)d_ws;
  bf16* qkbuf  = (bf16*)(ws);
  bf16* Vt     = (bf16*)(ws + (size_t)64 * 1024 * 1024);
  bf16* WqkvT  = (bf16*)(ws + (size_t)96 * 1024 * 1024);
  bf16* y      = WqkvT; // alias, sequenced
  bf16* WprojT = (bf16*)(ws + (size_t)128 * 1024 * 1024);
  bf16* xb     = (bf16*)d_out; // scratch until gemm2 overwrites

  cvt_bf16_k<<<dim3((Bz * T * Cdim) / (256 * 8)), 256, 0, stream>>>(x, xb);
  transpose_cvt_k<<<dim3(QKVC / 32, Cdim / 32), dim3(32, 8), 0, stream>>>(
      Wqkv, WqkvT, Cdim, QKVC);
  transpose_cvt_k<<<dim3(Cdim / 32, Cdim / 32), dim3(32, 8), 0, stream>>>(
      Wproj, WprojT, Cdim, Cdim);

  // qkv GEMM: q,k -> qkbuf; v -> Vt (scattered transposed)
  gemm256_k<false, true><<<dim3(QKVC / 256, (Bz * T) / 256), 512, 131072, stream>>>(
      xb, WqkvT, (void*)qkbuf, Vt, Bz * T, QKVC, Cdim, QKC);

  // causal flash attention (paired q-tiles: perfect load balance)
  attn_k<<<dim3(T / 256, NH, Bz), 512, 0, stream>>>(qkbuf, Vt, y);

  // out = y @ Wproj
  gemm256_k<true, false><<<dim3(Cdim / 256, (Bz * T) / 256), 512, 131072, stream>>>(
      y, WprojT, (void*)out, nullptr, Bz * T, Cdim, Cdim, Cdim);
}